// Round 1
// 3716.683 us; speedup vs baseline: 1.3301x; 1.3301x over previous
//
#include <hip/hip_runtime.h>
#include <hip/hip_bf16.h>
#include <math.h>

#define VOCAB  32000
#define EMBED  256
#define HIDDEN 512
#define BATCH  64
#define TCAP   32
#define SEQ    33      // T_CAP + 1
#define G4     2048    // 4 * HIDDEN
#define MROWS  2112    // BATCH * SEQ

typedef unsigned short ushort_t;

__device__ __forceinline__ float bf2f(ushort_t u) {
    union { unsigned int i; float f; } v;
    v.i = ((unsigned int)u) << 16;
    return v.f;
}

__device__ __forceinline__ void bfpair(unsigned int u, float& lo, float& hi) {
    union { unsigned int i; float f; } a, b;
    a.i = u << 16;
    b.i = u & 0xffff0000u;
    lo = a.f; hi = b.f;
}

// load 8 consecutive weights (either dtype) as fp32
template<bool BF>
__device__ __forceinline__ void ldw8(const void* p, size_t idx, float* w) {
    if constexpr (BF) {
        uint4 u = *(const uint4*)((const ushort_t*)p + idx);
        bfpair(u.x, w[0], w[1]); bfpair(u.y, w[2], w[3]);
        bfpair(u.z, w[4], w[5]); bfpair(u.w, w[6], w[7]);
    } else {
        float4 a = *(const float4*)((const float*)p + idx);
        float4 b = *(const float4*)((const float*)p + idx + 4);
        w[0]=a.x; w[1]=a.y; w[2]=a.z; w[3]=a.w;
        w[4]=b.x; w[5]=b.y; w[6]=b.z; w[7]=b.w;
    }
}

template<bool BF>
__device__ __forceinline__ float ldw1(const void* p, size_t i) {
    if constexpr (BF) return bf2f(((const ushort_t*)p)[i]);
    else return ((const float*)p)[i];
}

__device__ __forceinline__ float dot8f(const float* w, const float* h) {
    return w[0]*h[0]+w[1]*h[1]+w[2]*h[2]+w[3]*h[3]
         + w[4]*h[4]+w[5]*h[5]+w[6]*h[6]+w[7]*h[7];
}

__device__ __forceinline__ float sigm(float x) { return 1.0f / (1.0f + expf(-x)); }

// ---------------------------------------------------------------------------
// Dtype detector: low 16 bits of each fp32-word of `features`.
// bf16 data -> low half is a bf16 ~N(0,1): exponent in [113,131] nearly always.
// fp32 data -> low half is random mantissa bits: exponent uniform, ~7% hit.
// 8192 words is within bounds for both worlds (bf16 buffer = exactly 32KB).
// ---------------------------------------------------------------------------
__global__ void k_detect(const unsigned int* __restrict__ w, int* __restrict__ mode) {
    __shared__ int cnt[256];
    int c = 0;
    for (int i = threadIdx.x; i < 8192; i += 256) {
        unsigned int lo = w[i] & 0xffffu;
        int e = (lo >> 7) & 0xff;
        if (e >= 113 && e <= 131) c++;
    }
    cnt[threadIdx.x] = c;
    __syncthreads();
    for (int s = 128; s > 0; s >>= 1) {
        if (threadIdx.x < s) cnt[threadIdx.x] += cnt[threadIdx.x + s];
        __syncthreads();
    }
    if (threadIdx.x == 0) *mode = (cnt[0] > 6000) ? 1 : 0;   // 1 = bf16
}

// ---------------------------------------------------------------------------
// K1: xp[bt][g] = dot(x_bt, W_ih[g]) + b_ih[g] + b_hh[g]
// grid (8, 2112), block 256.
// ---------------------------------------------------------------------------
template<bool BF>
__global__ void k_xproj(const int* __restrict__ mode,
                        const void* __restrict__ features,
                        const int*  __restrict__ captions,
                        const void* __restrict__ embedding,
                        const void* __restrict__ W_ih,
                        const void* __restrict__ b_ih,
                        const void* __restrict__ b_hh,
                        float* __restrict__ xp) {
    if (*mode != (int)BF) return;
    __shared__ float xs[EMBED];
    int bt  = blockIdx.y;
    int b   = bt / SEQ;
    int t   = bt % SEQ;
    int tid = threadIdx.x;

    size_t src_off;
    const void* src;
    if (t == 0) { src = features;  src_off = (size_t)b * EMBED; }
    else        { src = embedding; src_off = (size_t)captions[b * TCAP + (t - 1)] * EMBED; }
    xs[tid] = ldw1<BF>(src, src_off + tid);
    __syncthreads();

    int g = blockIdx.x * 256 + tid;
    float acc = ldw1<BF>(b_ih, g) + ldw1<BF>(b_hh, g);
    size_t wbase = (size_t)g * EMBED;
    for (int e = 0; e < EMBED; e += 8) {
        float w[8];
        ldw8<BF>(W_ih, wbase + e, w);
        acc += dot8f(w, xs + e);
    }
    xp[(size_t)bt * G4 + g] = acc;
}

// ---------------------------------------------------------------------------
// K2: one LSTM step. grid (8, 16), block 256 = 64 j-lanes x 4 batches.
// Thread (jl, bb) computes all 4 gates for (b = by*4+bb, j = bx*64+jl).
// h_prev read from hs[t-1] (read-only this launch) -> race-free.
// c_buf[b][j] owned by exactly one thread per launch.
// ---------------------------------------------------------------------------
template<bool BF>
__global__ void k_step(const int* __restrict__ mode,
                       const float* __restrict__ xp,
                       const void* __restrict__ W_hh,
                       float* __restrict__ c_buf,
                       float* __restrict__ hs,
                       int t) {
    if (*mode != (int)BF) return;
    __shared__ float hsh[4][HIDDEN];
    int tid = threadIdx.x;
    int jl  = tid & 63, bb = tid >> 6;
    int j   = blockIdx.x * 64 + jl;
    int b   = blockIdx.y * 4 + bb;

    if (t > 0) {
        // stage h_prev for the 4 batches: 2048 floats, 2 float4/thread
        for (int r = 0; r < 2; r++) {
            int i4 = tid + r * 256;            // 0..511 float4 slots
            int sb = i4 >> 7, k4 = (i4 & 127) << 2;
            *(float4*)(&hsh[sb][k4]) =
                *(const float4*)(hs + ((size_t)(blockIdx.y * 4 + sb) * SEQ + (t - 1)) * HIDDEN + k4);
        }
        __syncthreads();
    }

    size_t xbase = ((size_t)b * SEQ + t) * G4;
    float ai = xp[xbase + j];
    float af = xp[xbase + HIDDEN + j];
    float ag = xp[xbase + 2 * HIDDEN + j];
    float ao = xp[xbase + 3 * HIDDEN + j];

    if (t > 0) {
        const float* hp = hsh[bb];
        size_t r0 = (size_t)j * HIDDEN;
        size_t r1 = (size_t)(HIDDEN + j) * HIDDEN;
        size_t r2 = (size_t)(2 * HIDDEN + j) * HIDDEN;
        size_t r3 = (size_t)(3 * HIDDEN + j) * HIDDEN;
        for (int k = 0; k < HIDDEN; k += 8) {
            float w[8];
            ldw8<BF>(W_hh, r0 + k, w); ai += dot8f(w, hp + k);
            ldw8<BF>(W_hh, r1 + k, w); af += dot8f(w, hp + k);
            ldw8<BF>(W_hh, r2 + k, w); ag += dot8f(w, hp + k);
            ldw8<BF>(W_hh, r3 + k, w); ao += dot8f(w, hp + k);
        }
    }

    float c_prev = (t > 0) ? c_buf[b * HIDDEN + j] : 0.0f;
    float c = sigm(af) * c_prev + sigm(ai) * tanhf(ag);
    float h = sigm(ao) * tanhf(c);
    c_buf[b * HIDDEN + j] = c;
    hs[((size_t)b * SEQ + t) * HIDDEN + j] = h;
}

// ---------------------------------------------------------------------------
// K3 (rewritten): logits = hs @ W_out^T + b_out.  M=2112, N=32000, K=512.
// LDS-tiled SGEMM: BM=128, BN=128, KC=32, block 256 threads (16 tm x 16 tn),
// 8x8 register tile/thread -> 64 FMA per 4 ds_read_b128.
// LDS rows use a split-swizzle layout: element (k,r) at [k][swz(r)] so each
// 8-float fragment is two contiguous float4s -> inner reads are 2-way
// (free) bank pattern; staging-write conflicts amortize over 2048 FMA/KC.
// Grid is XCD-chunked: all 17 m-blocks of an n-slice share bid%8 -> the
// 128-row W_out slice (256KB) stays hot in that XCD's L2 (vs 66x L3 re-read).
// ---------------------------------------------------------------------------
#define BM 128
#define BN 128
#define KC 32
#define NBN 250              // 32000 / 128
#define NBM 17               // ceil(2112 / 128)
#define LOGITS_GRID (8 * 32 * NBM)   // 8 XCDs x 32 padded n-slices/XCD x 17 = 4352

__device__ __forceinline__ int swz(int r) {   // bijective on 0..127
    return ((r >> 2) & 1) * 64 + (r >> 3) * 4 + (r & 3);
}

template<bool BF>
__global__ __launch_bounds__(256, 4)
void k_logits(const int* __restrict__ mode,
              const float* __restrict__ hs,
              const void* __restrict__ W_out,
              const void* __restrict__ b_out,
              void* __restrict__ out) {
    if (*mode != (int)BF) return;

    int bid = blockIdx.x;
    int xcd = bid & 7;
    int j8  = bid >> 3;            // 0..543
    int mb  = j8 % NBM;            // m-block, fastest -> same-XCD L2 reuse of W_out slice
    int nb  = xcd + 8 * (j8 / NBM);
    if (nb >= NBN) return;         // pad blocks (2.3%), uniform exit before barriers

    __shared__ float As[KC][BM];
    __shared__ float Bs[KC][BN];

    int t  = threadIdx.x;
    int tm = t >> 4;               // 0..15
    int tn = t & 15;               // 0..15
    int m_base = mb * BM;
    int n_base = nb * BN;

    float acc[8][8];
#pragma unroll
    for (int i = 0; i < 8; ++i)
#pragma unroll
        for (int q = 0; q < 8; ++q) acc[i][q] = 0.0f;

    for (int kt = 0; kt < HIDDEN / KC; ++kt) {
        __syncthreads();           // previous-iter readers done before overwrite

        // ---- stage A (hs): 128 x 32 f32, coalesced 128B row-chunks ----
#pragma unroll
        for (int i = 0; i < 4; ++i) {
            int flat = t + i * 256;        // float4 id 0..1023
            int m  = flat >> 3;            // 0..127
            int kq = flat & 7;             // 0..7
            int gm = m_base + m;
            float4 v = make_float4(0.f, 0.f, 0.f, 0.f);
            if (gm < MROWS)
                v = *(const float4*)(hs + (size_t)gm * HIDDEN + kt * KC + kq * 4);
            int s = swz(m);
            As[kq*4+0][s] = v.x; As[kq*4+1][s] = v.y;
            As[kq*4+2][s] = v.z; As[kq*4+3][s] = v.w;
        }

        // ---- stage B (W_out): 128 x 32, dtype-dependent ----
        if constexpr (BF) {
#pragma unroll
            for (int i = 0; i < 2; ++i) {
                int flat = t + i * 256;    // uint4 id 0..511 (8 bf16 each)
                int n  = flat >> 2;        // 0..127
                int ko = (flat & 3) * 8;   // 0,8,16,24
                const ushort_t* src = (const ushort_t*)W_out
                    + (size_t)(n_base + n) * HIDDEN + kt * KC + ko;
                uint4 u = *(const uint4*)src;
                float w[8];
                bfpair(u.x, w[0], w[1]); bfpair(u.y, w[2], w[3]);
                bfpair(u.z, w[4], w[5]); bfpair(u.w, w[6], w[7]);
                int s = swz(n);
#pragma unroll
                for (int d = 0; d < 8; ++d) Bs[ko + d][s] = w[d];
            }
        } else {
#pragma unroll
            for (int i = 0; i < 4; ++i) {
                int flat = t + i * 256;
                int n  = flat >> 3;
                int kq = flat & 7;
                const float* src = (const float*)W_out
                    + (size_t)(n_base + n) * HIDDEN + kt * KC + kq * 4;
                float4 v = *(const float4*)src;
                int s = swz(n);
                Bs[kq*4+0][s] = v.x; Bs[kq*4+1][s] = v.y;
                Bs[kq*4+2][s] = v.z; Bs[kq*4+3][s] = v.w;
            }
        }
        __syncthreads();

        // ---- inner: 32 k-steps, 64 FMA per 4 ds_read_b128 ----
#pragma unroll 8
        for (int k = 0; k < KC; ++k) {
            float4 a0 = *(const float4*)&As[k][tm * 4];
            float4 a1 = *(const float4*)&As[k][64 + tm * 4];
            float4 b0 = *(const float4*)&Bs[k][tn * 4];
            float4 b1 = *(const float4*)&Bs[k][64 + tn * 4];
            float a[8] = {a0.x, a0.y, a0.z, a0.w, a1.x, a1.y, a1.z, a1.w};
            float b[8] = {b0.x, b0.y, b0.z, b0.w, b1.x, b1.y, b1.z, b1.w};
#pragma unroll
            for (int i = 0; i < 8; ++i)
#pragma unroll
                for (int q = 0; q < 8; ++q)
                    acc[i][q] = fmaf(a[i], b[q], acc[i][q]);
        }
    }

    // ---- epilogue: + bias, store 8x8 (16B-aligned vector stores) ----
    float bias[8];
#pragma unroll
    for (int q = 0; q < 8; ++q) bias[q] = ldw1<BF>(b_out, n_base + tn * 8 + q);

#pragma unroll
    for (int i = 0; i < 8; ++i) {
        int gm = m_base + tm * 8 + i;
        if (gm >= MROWS) continue;
        size_t o = (size_t)gm * VOCAB + n_base + tn * 8;
        if constexpr (BF) {
            unsigned int p[4];
#pragma unroll
            for (int q = 0; q < 4; ++q) {
                __hip_bfloat16 lo = __float2bfloat16(acc[i][2*q]   + bias[2*q]);
                __hip_bfloat16 hi = __float2bfloat16(acc[i][2*q+1] + bias[2*q+1]);
                unsigned short ul = *(unsigned short*)&lo;
                unsigned short uh = *(unsigned short*)&hi;
                p[q] = (unsigned int)ul | ((unsigned int)uh << 16);
            }
            *(uint4*)((__hip_bfloat16*)out + o) = make_uint4(p[0], p[1], p[2], p[3]);
        } else {
            float* op = (float*)out + o;
            *(float4*)(op + 0) = make_float4(acc[i][0]+bias[0], acc[i][1]+bias[1],
                                             acc[i][2]+bias[2], acc[i][3]+bias[3]);
            *(float4*)(op + 4) = make_float4(acc[i][4]+bias[4], acc[i][5]+bias[5],
                                             acc[i][6]+bias[6], acc[i][7]+bias[7]);
        }
    }
}

// ---------------------------------------------------------------------------
extern "C" void kernel_launch(void* const* d_in, const int* in_sizes, int n_in,
                              void* d_out, int out_size, void* d_ws, size_t ws_size,
                              hipStream_t stream) {
    const void* features  = d_in[0];
    const int*  captions  = (const int*)d_in[1];
    const void* embedding = d_in[3];
    const void* W_ih      = d_in[4];
    const void* W_hh      = d_in[5];
    const void* b_ih      = d_in[6];
    const void* b_hh      = d_in[7];
    const void* W_out     = d_in[8];
    const void* b_out     = d_in[9];

    // ws: xp[2112][2048] f32 | hs[2112][512] f32 | c_buf[64][512] f32 | mode
    char* ws = (char*)d_ws;
    float* xp    = (float*)ws;
    float* hs    = (float*)(ws + (size_t)2112 * G4 * 4);
    float* c_buf = (float*)(ws + (size_t)2112 * G4 * 4 + (size_t)2112 * HIDDEN * 4);
    int*   mode  = (int*)(ws + (size_t)2112 * G4 * 4 + (size_t)2112 * HIDDEN * 4
                             + (size_t)BATCH * HIDDEN * 4);

    k_detect<<<1, 256, 0, stream>>>((const unsigned int*)features, mode);

    k_xproj<false><<<dim3(8, BATCH * SEQ), 256, 0, stream>>>(
        mode, features, captions, embedding, W_ih, b_ih, b_hh, xp);
    k_xproj<true><<<dim3(8, BATCH * SEQ), 256, 0, stream>>>(
        mode, features, captions, embedding, W_ih, b_ih, b_hh, xp);

    for (int t = 0; t < SEQ; t++) {
        k_step<false><<<dim3(8, BATCH / 4), 256, 0, stream>>>(mode, xp, W_hh, c_buf, hs, t);
        k_step<true><<<dim3(8, BATCH / 4), 256, 0, stream>>>(mode, xp, W_hh, c_buf, hs, t);
    }

    k_logits<false><<<dim3(LOGITS_GRID), 256, 0, stream>>>(mode, hs, W_out, b_out, d_out);
    k_logits<true><<<dim3(LOGITS_GRID), 256, 0, stream>>>(mode, hs, W_out, b_out, d_out);
}

// Round 2
// 2798.741 us; speedup vs baseline: 1.7664x; 1.3280x over previous
//
#include <hip/hip_runtime.h>
#include <hip/hip_bf16.h>
#include <math.h>

#define VOCAB  32000
#define EMBED  256
#define HIDDEN 512
#define BATCH  64
#define TCAP   32
#define SEQ    33      // T_CAP + 1
#define G4     2048    // 4 * HIDDEN
#define MROWS  2112    // BATCH * SEQ

typedef unsigned short ushort_t;

__device__ __forceinline__ float bf2f(ushort_t u) {
    union { unsigned int i; float f; } v;
    v.i = ((unsigned int)u) << 16;
    return v.f;
}

__device__ __forceinline__ void bfpair(unsigned int u, float& lo, float& hi) {
    union { unsigned int i; float f; } a, b;
    a.i = u << 16;
    b.i = u & 0xffff0000u;
    lo = a.f; hi = b.f;
}

// load 8 consecutive weights (either dtype) as fp32
template<bool BF>
__device__ __forceinline__ void ldw8(const void* p, size_t idx, float* w) {
    if constexpr (BF) {
        uint4 u = *(const uint4*)((const ushort_t*)p + idx);
        bfpair(u.x, w[0], w[1]); bfpair(u.y, w[2], w[3]);
        bfpair(u.z, w[4], w[5]); bfpair(u.w, w[6], w[7]);
    } else {
        float4 a = *(const float4*)((const float*)p + idx);
        float4 b = *(const float4*)((const float*)p + idx + 4);
        w[0]=a.x; w[1]=a.y; w[2]=a.z; w[3]=a.w;
        w[4]=b.x; w[5]=b.y; w[6]=b.z; w[7]=b.w;
    }
}

template<bool BF>
__device__ __forceinline__ float ldw1(const void* p, size_t i) {
    if constexpr (BF) return bf2f(((const ushort_t*)p)[i]);
    else return ((const float*)p)[i];
}

__device__ __forceinline__ float dot8f(const float* w, const float* h) {
    return w[0]*h[0]+w[1]*h[1]+w[2]*h[2]+w[3]*h[3]
         + w[4]*h[4]+w[5]*h[5]+w[6]*h[6]+w[7]*h[7];
}

__device__ __forceinline__ float sigm(float x) { return 1.0f / (1.0f + expf(-x)); }

// ---------------------------------------------------------------------------
// Dtype detector (unchanged)
// ---------------------------------------------------------------------------
__global__ void k_detect(const unsigned int* __restrict__ w, int* __restrict__ mode) {
    __shared__ int cnt[256];
    int c = 0;
    for (int i = threadIdx.x; i < 8192; i += 256) {
        unsigned int lo = w[i] & 0xffffu;
        int e = (lo >> 7) & 0xff;
        if (e >= 113 && e <= 131) c++;
    }
    cnt[threadIdx.x] = c;
    __syncthreads();
    for (int s = 128; s > 0; s >>= 1) {
        if (threadIdx.x < s) cnt[threadIdx.x] += cnt[threadIdx.x + s];
        __syncthreads();
    }
    if (threadIdx.x == 0) *mode = (cnt[0] > 6000) ? 1 : 0;   // 1 = bf16
}

// ---------------------------------------------------------------------------
// K1: xp[bt][g] = dot(x_bt, W_ih[g]) + b_ih[g] + b_hh[g]  (unchanged)
// ---------------------------------------------------------------------------
template<bool BF>
__global__ void k_xproj(const int* __restrict__ mode,
                        const void* __restrict__ features,
                        const int*  __restrict__ captions,
                        const void* __restrict__ embedding,
                        const void* __restrict__ W_ih,
                        const void* __restrict__ b_ih,
                        const void* __restrict__ b_hh,
                        float* __restrict__ xp) {
    if (*mode != (int)BF) return;
    __shared__ float xs[EMBED];
    int bt  = blockIdx.y;
    int b   = bt / SEQ;
    int t   = bt % SEQ;
    int tid = threadIdx.x;

    size_t src_off;
    const void* src;
    if (t == 0) { src = features;  src_off = (size_t)b * EMBED; }
    else        { src = embedding; src_off = (size_t)captions[b * TCAP + (t - 1)] * EMBED; }
    xs[tid] = ldw1<BF>(src, src_off + tid);
    __syncthreads();

    int g = blockIdx.x * 256 + tid;
    float acc = ldw1<BF>(b_ih, g) + ldw1<BF>(b_hh, g);
    size_t wbase = (size_t)g * EMBED;
    for (int e = 0; e < EMBED; e += 8) {
        float w[8];
        ldw8<BF>(W_ih, wbase + e, w);
        acc += dot8f(w, xs + e);
    }
    xp[(size_t)bt * G4 + g] = acc;
}

// ---------------------------------------------------------------------------
// W_hh repack: k-blocked layout so k_step2's lane-j loads are coalesced.
// fp32: WT4[k>>2][g][k&3]  (16B granule per (k4,g))
// bf16: WT8[k>>3][g][k&7]  (16B granule per (k8,g))
// Runtime-uniform mode branch; one launch.
// ---------------------------------------------------------------------------
__global__ void k_wtr(const int* __restrict__ mode,
                      const void* __restrict__ Whh,
                      void* __restrict__ WT) {
    const bool bf = (*mode != 0);
    for (int r = 0; r < 4; r++) {
        size_t e = (size_t)blockIdx.x * 1024 + r * 256 + threadIdx.x;  // 0..2048*512-1
        int g = (int)(e >> 9);
        int k = (int)(e & 511);
        if (bf) {
            ushort_t w = ((const ushort_t*)Whh)[e];
            ((ushort_t*)WT)[((size_t)(k >> 3) << 14) + ((size_t)g << 3) + (k & 7)] = w;
        } else {
            float w = ((const float*)Whh)[e];
            ((float*)WT)[((size_t)(k >> 2) << 13) + ((size_t)g << 2) + (k & 3)] = w;
        }
    }
}

// ---------------------------------------------------------------------------
// K2 v2: one LSTM step, coalesced W reads from repacked WT.
// grid (8, 16), block 256 = 64 j-lanes x 4 batches. Runtime-uniform mode.
// Per iter: 4 gate-granules (16B each, lane-consecutive -> 1KB/inst) + LDS h.
// ---------------------------------------------------------------------------
__global__ __launch_bounds__(256)
void k_step2(const int* __restrict__ mode,
             const float* __restrict__ xp,
             const void* __restrict__ WT,
             float* __restrict__ c_buf,
             float* __restrict__ hs,
             int t) {
    const bool bf = (*mode != 0);
    __shared__ float hsh[4][HIDDEN];
    int tid = threadIdx.x;
    int jl  = tid & 63, bb = tid >> 6;
    int j   = blockIdx.x * 64 + jl;
    int b   = blockIdx.y * 4 + bb;

    if (t > 0) {
        for (int r = 0; r < 2; r++) {
            int i4 = tid + r * 256;
            int sb = i4 >> 7, k4 = (i4 & 127) << 2;
            *(float4*)(&hsh[sb][k4]) =
                *(const float4*)(hs + ((size_t)(blockIdx.y * 4 + sb) * SEQ + (t - 1)) * HIDDEN + k4);
        }
        __syncthreads();
    }

    size_t xbase = ((size_t)b * SEQ + t) * G4;
    float ai = xp[xbase + j];
    float af = xp[xbase + HIDDEN + j];
    float ag = xp[xbase + 2 * HIDDEN + j];
    float ao = xp[xbase + 3 * HIDDEN + j];

    if (t > 0) {
        const float* hp = hsh[bb];
        if (bf) {
            const ushort_t* wt = (const ushort_t*)WT;
            const ushort_t* p0 = wt + (size_t)j * 8;
            const ushort_t* p1 = wt + (size_t)(HIDDEN + j) * 8;
            const ushort_t* p2 = wt + (size_t)(2 * HIDDEN + j) * 8;
            const ushort_t* p3 = wt + (size_t)(3 * HIDDEN + j) * 8;
#pragma unroll 2
            for (int k8 = 0; k8 < 64; ++k8) {
                size_t pb = (size_t)k8 * 16384;
                uint4 u0 = *(const uint4*)(p0 + pb);
                uint4 u1 = *(const uint4*)(p1 + pb);
                uint4 u2 = *(const uint4*)(p2 + pb);
                uint4 u3 = *(const uint4*)(p3 + pb);
                float4 h0 = *(const float4*)(hp + k8 * 8);
                float4 h1 = *(const float4*)(hp + k8 * 8 + 4);
                float w[8];
                bfpair(u0.x, w[0], w[1]); bfpair(u0.y, w[2], w[3]);
                bfpair(u0.z, w[4], w[5]); bfpair(u0.w, w[6], w[7]);
                ai += w[0]*h0.x + w[1]*h0.y + w[2]*h0.z + w[3]*h0.w
                    + w[4]*h1.x + w[5]*h1.y + w[6]*h1.z + w[7]*h1.w;
                bfpair(u1.x, w[0], w[1]); bfpair(u1.y, w[2], w[3]);
                bfpair(u1.z, w[4], w[5]); bfpair(u1.w, w[6], w[7]);
                af += w[0]*h0.x + w[1]*h0.y + w[2]*h0.z + w[3]*h0.w
                    + w[4]*h1.x + w[5]*h1.y + w[6]*h1.z + w[7]*h1.w;
                bfpair(u2.x, w[0], w[1]); bfpair(u2.y, w[2], w[3]);
                bfpair(u2.z, w[4], w[5]); bfpair(u2.w, w[6], w[7]);
                ag += w[0]*h0.x + w[1]*h0.y + w[2]*h0.z + w[3]*h0.w
                    + w[4]*h1.x + w[5]*h1.y + w[6]*h1.z + w[7]*h1.w;
                bfpair(u3.x, w[0], w[1]); bfpair(u3.y, w[2], w[3]);
                bfpair(u3.z, w[4], w[5]); bfpair(u3.w, w[6], w[7]);
                ao += w[0]*h0.x + w[1]*h0.y + w[2]*h0.z + w[3]*h0.w
                    + w[4]*h1.x + w[5]*h1.y + w[6]*h1.z + w[7]*h1.w;
            }
        } else {
            const float* wt = (const float*)WT;
            const float* p0 = wt + (size_t)j * 4;
            const float* p1 = wt + (size_t)(HIDDEN + j) * 4;
            const float* p2 = wt + (size_t)(2 * HIDDEN + j) * 4;
            const float* p3 = wt + (size_t)(3 * HIDDEN + j) * 4;
#pragma unroll 4
            for (int k4 = 0; k4 < 128; ++k4) {
                size_t pb = (size_t)k4 * 8192;
                float4 wi = *(const float4*)(p0 + pb);
                float4 wf = *(const float4*)(p1 + pb);
                float4 wg = *(const float4*)(p2 + pb);
                float4 wo = *(const float4*)(p3 + pb);
                float4 hv = *(const float4*)(hp + k4 * 4);
                ai += wi.x*hv.x + wi.y*hv.y + wi.z*hv.z + wi.w*hv.w;
                af += wf.x*hv.x + wf.y*hv.y + wf.z*hv.z + wf.w*hv.w;
                ag += wg.x*hv.x + wg.y*hv.y + wg.z*hv.z + wg.w*hv.w;
                ao += wo.x*hv.x + wo.y*hv.y + wo.z*hv.z + wo.w*hv.w;
            }
        }
    }

    float c_prev = (t > 0) ? c_buf[b * HIDDEN + j] : 0.0f;
    float c = sigm(af) * c_prev + sigm(ai) * tanhf(ag);
    float h = sigm(ao) * tanhf(c);
    c_buf[b * HIDDEN + j] = c;
    hs[((size_t)b * SEQ + t) * HIDDEN + j] = h;
}

// ---------------------------------------------------------------------------
// K2 fallback (old, W_hh direct) — used only if workspace too small for WT.
// ---------------------------------------------------------------------------
template<bool BF>
__global__ void k_step(const int* __restrict__ mode,
                       const float* __restrict__ xp,
                       const void* __restrict__ W_hh,
                       float* __restrict__ c_buf,
                       float* __restrict__ hs,
                       int t) {
    if (*mode != (int)BF) return;
    __shared__ float hsh[4][HIDDEN];
    int tid = threadIdx.x;
    int jl  = tid & 63, bb = tid >> 6;
    int j   = blockIdx.x * 64 + jl;
    int b   = blockIdx.y * 4 + bb;

    if (t > 0) {
        for (int r = 0; r < 2; r++) {
            int i4 = tid + r * 256;
            int sb = i4 >> 7, k4 = (i4 & 127) << 2;
            *(float4*)(&hsh[sb][k4]) =
                *(const float4*)(hs + ((size_t)(blockIdx.y * 4 + sb) * SEQ + (t - 1)) * HIDDEN + k4);
        }
        __syncthreads();
    }

    size_t xbase = ((size_t)b * SEQ + t) * G4;
    float ai = xp[xbase + j];
    float af = xp[xbase + HIDDEN + j];
    float ag = xp[xbase + 2 * HIDDEN + j];
    float ao = xp[xbase + 3 * HIDDEN + j];

    if (t > 0) {
        const float* hp = hsh[bb];
        size_t r0 = (size_t)j * HIDDEN;
        size_t r1 = (size_t)(HIDDEN + j) * HIDDEN;
        size_t r2 = (size_t)(2 * HIDDEN + j) * HIDDEN;
        size_t r3 = (size_t)(3 * HIDDEN + j) * HIDDEN;
        for (int k = 0; k < HIDDEN; k += 8) {
            float w[8];
            ldw8<BF>(W_hh, r0 + k, w); ai += dot8f(w, hp + k);
            ldw8<BF>(W_hh, r1 + k, w); af += dot8f(w, hp + k);
            ldw8<BF>(W_hh, r2 + k, w); ag += dot8f(w, hp + k);
            ldw8<BF>(W_hh, r3 + k, w); ao += dot8f(w, hp + k);
        }
    }

    float c_prev = (t > 0) ? c_buf[b * HIDDEN + j] : 0.0f;
    float c = sigm(af) * c_prev + sigm(ai) * tanhf(ag);
    float h = sigm(ao) * tanhf(c);
    c_buf[b * HIDDEN + j] = c;
    hs[((size_t)b * SEQ + t) * HIDDEN + j] = h;
}

// ---------------------------------------------------------------------------
// K3 v3: logits = hs @ W_out^T + b_out.  M=2112, N=32000, K=512.
// Same 128x128x32 tiling, but CONFLICT-FREE staging:
//   - global: 4 scalar loads (4 rows, same k) per quad -> 2x128B runs/inst
//   - LDS: one ds_write_b128 per quad, column-quad XOR-swizzled by (k&7)
// Inner reads apply the same XOR: per 16-lane phase, b-reads hit 8 distinct
// bank-groups x2 rows (free 2-way), a-reads are phase-broadcast.
// Fragment mapping: logical quad q holds rows 4q..4q+3; thread (tm,tn) owns
// m in {4tm..+3, 64+4tm..+3}, n in {4tn..+3, 64+4tn..+3}.
// ---------------------------------------------------------------------------
#define BM 128
#define BN 128
#define KC 32
#define NBN 250              // 32000 / 128
#define NBM 17               // ceil(2112 / 128)
#define LOGITS_GRID (8 * 32 * NBM)   // 4352

template<bool BF>
__global__ __launch_bounds__(256, 4)
void k_logits(const int* __restrict__ mode,
              const float* __restrict__ hs,
              const void* __restrict__ W_out,
              const void* __restrict__ b_out,
              void* __restrict__ out) {
    if (*mode != (int)BF) return;

    int bid = blockIdx.x;
    int xcd = bid & 7;
    int j8  = bid >> 3;
    int mb  = j8 % NBM;
    int nb  = xcd + 8 * (j8 / NBM);
    if (nb >= NBN) return;

    __shared__ float As[KC][BM];
    __shared__ float Bs[KC][BN];

    int t  = threadIdx.x;
    int tm = t >> 4;               // 0..15
    int tn = t & 15;               // 0..15
    int kk = t & 31;               // staging k-lane
    int mg = t >> 5;               // staging quad-group 0..7
    int m_base = mb * BM;
    int n_base = nb * BN;

    float acc[8][8];
#pragma unroll
    for (int i = 0; i < 8; ++i)
#pragma unroll
        for (int q = 0; q < 8; ++q) acc[i][q] = 0.0f;

    int sws = kk & 7;              // staging swizzle

    for (int kt = 0; kt < HIDDEN / KC; ++kt) {
        __syncthreads();

        // ---- stage A (hs): per quad, 4 scalar loads + 1 swizzled b128 write
#pragma unroll
        for (int r = 0; r < 4; ++r) {
            int q = mg + 8 * r;
            float v[4];
#pragma unroll
            for (int i = 0; i < 4; ++i) {
                int gm = m_base + q * 4 + i;
                v[i] = (gm < MROWS) ? hs[(size_t)gm * HIDDEN + kt * KC + kk] : 0.0f;
            }
            int pq = (mg ^ sws) + 8 * r;
            *(float4*)&As[kk][pq * 4] = make_float4(v[0], v[1], v[2], v[3]);
        }

        // ---- stage B (W_out): same pattern, dtype-dependent scalar loads
#pragma unroll
        for (int r = 0; r < 4; ++r) {
            int q = mg + 8 * r;
            float v[4];
#pragma unroll
            for (int i = 0; i < 4; ++i) {
                size_t gi = (size_t)(n_base + q * 4 + i) * HIDDEN + kt * KC + kk;
                if constexpr (BF) v[i] = bf2f(((const ushort_t*)W_out)[gi]);
                else              v[i] = ((const float*)W_out)[gi];
            }
            int pq = (mg ^ sws) + 8 * r;
            *(float4*)&Bs[kk][pq * 4] = make_float4(v[0], v[1], v[2], v[3]);
        }
        __syncthreads();

        // ---- inner: 32 k-steps, 64 FMA per 4 ds_read_b128 (conflict-free)
#pragma unroll 8
        for (int k = 0; k < KC; ++k) {
            int sw = k & 7;
            int am = tm ^ sw;      // 0..15 (sw only touches low 3 bits)
            int bn = tn ^ sw;
            float4 a0 = *(const float4*)&As[k][am * 4];
            float4 a1 = *(const float4*)&As[k][(16 + am) * 4];
            float4 b0 = *(const float4*)&Bs[k][bn * 4];
            float4 b1 = *(const float4*)&Bs[k][(16 + bn) * 4];
            float a[8] = {a0.x, a0.y, a0.z, a0.w, a1.x, a1.y, a1.z, a1.w};
            float b[8] = {b0.x, b0.y, b0.z, b0.w, b1.x, b1.y, b1.z, b1.w};
#pragma unroll
            for (int i = 0; i < 8; ++i)
#pragma unroll
                for (int q = 0; q < 8; ++q)
                    acc[i][q] = fmaf(a[i], b[q], acc[i][q]);
        }
    }

    // ---- epilogue: + bias, store two float4-groups per m-row ----
    float bias[8];
#pragma unroll
    for (int q = 0; q < 4; ++q) bias[q]     = ldw1<BF>(b_out, n_base + 4 * tn + q);
#pragma unroll
    for (int q = 0; q < 4; ++q) bias[4 + q] = ldw1<BF>(b_out, n_base + 64 + 4 * tn + q);

#pragma unroll
    for (int i = 0; i < 8; ++i) {
        int gm = m_base + ((i < 4) ? (4 * tm + i) : (64 + 4 * tm + (i - 4)));
        if (gm >= MROWS) continue;
        size_t o0 = (size_t)gm * VOCAB + n_base + 4 * tn;
        size_t o1 = (size_t)gm * VOCAB + n_base + 64 + 4 * tn;
        if constexpr (BF) {
            unsigned int p0[2], p1[2];
#pragma unroll
            for (int q = 0; q < 2; ++q) {
                __hip_bfloat16 lo = __float2bfloat16(acc[i][2*q]   + bias[2*q]);
                __hip_bfloat16 hi = __float2bfloat16(acc[i][2*q+1] + bias[2*q+1]);
                unsigned short ul = *(unsigned short*)&lo;
                unsigned short uh = *(unsigned short*)&hi;
                p0[q] = (unsigned int)ul | ((unsigned int)uh << 16);
            }
#pragma unroll
            for (int q = 0; q < 2; ++q) {
                __hip_bfloat16 lo = __float2bfloat16(acc[i][4+2*q]   + bias[4+2*q]);
                __hip_bfloat16 hi = __float2bfloat16(acc[i][4+2*q+1] + bias[4+2*q+1]);
                unsigned short ul = *(unsigned short*)&lo;
                unsigned short uh = *(unsigned short*)&hi;
                p1[q] = (unsigned int)ul | ((unsigned int)uh << 16);
            }
            *(uint2*)((__hip_bfloat16*)out + o0) = make_uint2(p0[0], p0[1]);
            *(uint2*)((__hip_bfloat16*)out + o1) = make_uint2(p1[0], p1[1]);
        } else {
            float* op = (float*)out;
            *(float4*)(op + o0) = make_float4(acc[i][0]+bias[0], acc[i][1]+bias[1],
                                              acc[i][2]+bias[2], acc[i][3]+bias[3]);
            *(float4*)(op + o1) = make_float4(acc[i][4]+bias[4], acc[i][5]+bias[5],
                                              acc[i][6]+bias[6], acc[i][7]+bias[7]);
        }
    }
}

// ---------------------------------------------------------------------------
extern "C" void kernel_launch(void* const* d_in, const int* in_sizes, int n_in,
                              void* d_out, int out_size, void* d_ws, size_t ws_size,
                              hipStream_t stream) {
    const void* features  = d_in[0];
    const int*  captions  = (const int*)d_in[1];
    const void* embedding = d_in[3];
    const void* W_ih      = d_in[4];
    const void* W_hh      = d_in[5];
    const void* b_ih      = d_in[6];
    const void* b_hh      = d_in[7];
    const void* W_out     = d_in[8];
    const void* b_out     = d_in[9];

    // ws layout: xp[2112][2048] f32 | hs[2112][512] f32 | c_buf[64][512] f32 |
    //            mode (int) | pad | WT (4MB repacked W_hh)
    char* ws = (char*)d_ws;
    const size_t XP_OFF = 0;
    const size_t HS_OFF = (size_t)2112 * G4 * 4;                  // 17,301,504
    const size_t CB_OFF = HS_OFF + (size_t)2112 * HIDDEN * 4;     // 21,626,880
    const size_t MODE_OFF = CB_OFF + (size_t)BATCH * HIDDEN * 4;  // 21,757,952
    const size_t WT_OFF = MODE_OFF + 16;                          // 21,757,968 (16B aligned)
    const size_t NEED = WT_OFF + (size_t)4 * 1024 * 1024;         // 25,952,272

    float* xp    = (float*)(ws + XP_OFF);
    float* hs    = (float*)(ws + HS_OFF);
    float* c_buf = (float*)(ws + CB_OFF);
    int*   mode  = (int*)(ws + MODE_OFF);
    void*  WT    = (void*)(ws + WT_OFF);

    const bool fast = (ws_size >= NEED);

    k_detect<<<1, 256, 0, stream>>>((const unsigned int*)features, mode);

    if (fast)
        k_wtr<<<1024, 256, 0, stream>>>(mode, W_hh, WT);

    k_xproj<false><<<dim3(8, BATCH * SEQ), 256, 0, stream>>>(
        mode, features, captions, embedding, W_ih, b_ih, b_hh, xp);
    k_xproj<true><<<dim3(8, BATCH * SEQ), 256, 0, stream>>>(
        mode, features, captions, embedding, W_ih, b_ih, b_hh, xp);

    for (int t = 0; t < SEQ; t++) {
        if (fast) {
            k_step2<<<dim3(8, BATCH / 4), 256, 0, stream>>>(mode, xp, WT, c_buf, hs, t);
        } else {
            k_step<false><<<dim3(8, BATCH / 4), 256, 0, stream>>>(mode, xp, W_hh, c_buf, hs, t);
            k_step<true><<<dim3(8, BATCH / 4), 256, 0, stream>>>(mode, xp, W_hh, c_buf, hs, t);
        }
    }

    k_logits<false><<<dim3(LOGITS_GRID), 256, 0, stream>>>(mode, hs, W_out, b_out, d_out);
    k_logits<true><<<dim3(LOGITS_GRID), 256, 0, stream>>>(mode, hs, W_out, b_out, d_out);
}

// Round 4
// 1995.756 us; speedup vs baseline: 2.4771x; 1.4023x over previous
//
#include <hip/hip_runtime.h>
#include <hip/hip_bf16.h>
#include <math.h>

#define VOCAB  32000
#define EMBED  256
#define HIDDEN 512
#define BATCH  64
#define TCAP   32
#define SEQ    33      // T_CAP + 1
#define G4     2048    // 4 * HIDDEN
#define MROWS  2112    // BATCH * SEQ

typedef unsigned short ushort_t;

__device__ __forceinline__ float bf2f(ushort_t u) {
    union { unsigned int i; float f; } v;
    v.i = ((unsigned int)u) << 16;
    return v.f;
}

__device__ __forceinline__ void bfpair(unsigned int u, float& lo, float& hi) {
    union { unsigned int i; float f; } a, b;
    a.i = u << 16;
    b.i = u & 0xffff0000u;
    lo = a.f; hi = b.f;
}

// load 8 consecutive weights (either dtype) as fp32
template<bool BF>
__device__ __forceinline__ void ldw8(const void* p, size_t idx, float* w) {
    if constexpr (BF) {
        uint4 u = *(const uint4*)((const ushort_t*)p + idx);
        bfpair(u.x, w[0], w[1]); bfpair(u.y, w[2], w[3]);
        bfpair(u.z, w[4], w[5]); bfpair(u.w, w[6], w[7]);
    } else {
        float4 a = *(const float4*)((const float*)p + idx);
        float4 b = *(const float4*)((const float*)p + idx + 4);
        w[0]=a.x; w[1]=a.y; w[2]=a.z; w[3]=a.w;
        w[4]=b.x; w[5]=b.y; w[6]=b.z; w[7]=b.w;
    }
}

template<bool BF>
__device__ __forceinline__ float ldw1(const void* p, size_t i) {
    if constexpr (BF) return bf2f(((const ushort_t*)p)[i]);
    else return ((const float*)p)[i];
}

__device__ __forceinline__ float dot8f(const float* w, const float* h) {
    return w[0]*h[0]+w[1]*h[1]+w[2]*h[2]+w[3]*h[3]
         + w[4]*h[4]+w[5]*h[5]+w[6]*h[6]+w[7]*h[7];
}

__device__ __forceinline__ float sigm(float x) { return 1.0f / (1.0f + expf(-x)); }

// ---------------------------------------------------------------------------
// Dtype detector (unchanged)
// ---------------------------------------------------------------------------
__global__ void k_detect(const unsigned int* __restrict__ w, int* __restrict__ mode) {
    __shared__ int cnt[256];
    int c = 0;
    for (int i = threadIdx.x; i < 8192; i += 256) {
        unsigned int lo = w[i] & 0xffffu;
        int e = (lo >> 7) & 0xff;
        if (e >= 113 && e <= 131) c++;
    }
    cnt[threadIdx.x] = c;
    __syncthreads();
    for (int s = 128; s > 0; s >>= 1) {
        if (threadIdx.x < s) cnt[threadIdx.x] += cnt[threadIdx.x + s];
        __syncthreads();
    }
    if (threadIdx.x == 0) *mode = (cnt[0] > 6000) ? 1 : 0;   // 1 = bf16
}

// ---------------------------------------------------------------------------
// K1: xp[bt][g] = dot(x_bt, W_ih[g]) + b_ih[g] + b_hh[g]  (unchanged)
// ---------------------------------------------------------------------------
template<bool BF>
__global__ void k_xproj(const int* __restrict__ mode,
                        const void* __restrict__ features,
                        const int*  __restrict__ captions,
                        const void* __restrict__ embedding,
                        const void* __restrict__ W_ih,
                        const void* __restrict__ b_ih,
                        const void* __restrict__ b_hh,
                        float* __restrict__ xp) {
    if (*mode != (int)BF) return;
    __shared__ float xs[EMBED];
    int bt  = blockIdx.y;
    int b   = bt / SEQ;
    int t   = bt % SEQ;
    int tid = threadIdx.x;

    size_t src_off;
    const void* src;
    if (t == 0) { src = features;  src_off = (size_t)b * EMBED; }
    else        { src = embedding; src_off = (size_t)captions[b * TCAP + (t - 1)] * EMBED; }
    xs[tid] = ldw1<BF>(src, src_off + tid);
    __syncthreads();

    int g = blockIdx.x * 256 + tid;
    float acc = ldw1<BF>(b_ih, g) + ldw1<BF>(b_hh, g);
    size_t wbase = (size_t)g * EMBED;
    for (int e = 0; e < EMBED; e += 8) {
        float w[8];
        ldw8<BF>(W_ih, wbase + e, w);
        acc += dot8f(w, xs + e);
    }
    xp[(size_t)bt * G4 + g] = acc;
}

// ---------------------------------------------------------------------------
// W_hh repack (unchanged): k-blocked so k_step's lane-j loads are coalesced.
// fp32: WT4[k>>2][g][k&3]; bf16: WT8[k>>3][g][k&7]
// ---------------------------------------------------------------------------
__global__ void k_wtr(const int* __restrict__ mode,
                      const void* __restrict__ Whh,
                      void* __restrict__ WT) {
    const bool bf = (*mode != 0);
    for (int r = 0; r < 4; r++) {
        size_t e = (size_t)blockIdx.x * 1024 + r * 256 + threadIdx.x;
        int g = (int)(e >> 9);
        int k = (int)(e & 511);
        if (bf) {
            ushort_t w = ((const ushort_t*)Whh)[e];
            ((ushort_t*)WT)[((size_t)(k >> 3) << 14) + ((size_t)g << 3) + (k & 7)] = w;
        } else {
            float w = ((const float*)Whh)[e];
            ((float*)WT)[((size_t)(k >> 2) << 13) + ((size_t)g << 2) + (k & 3)] = w;
        }
    }
}

// ---------------------------------------------------------------------------
// K2 v3: one LSTM step. grid (16,16) = 256 blocks (all CUs busy), block 256 =
// 32 j-lanes x 4 batches x 2 k-halves. Split-K doubles in-flight loads per
// unit work; partials combined via LDS. kh==0 thread finishes the gate math.
// ---------------------------------------------------------------------------
__global__ __launch_bounds__(256)
void k_step3(const int* __restrict__ mode,
             const float* __restrict__ xp,
             const void* __restrict__ WT,
             float* __restrict__ c_buf,
             float* __restrict__ hs,
             int t) {
    const bool bf = (*mode != 0);
    __shared__ float hsh[4][HIDDEN];      // 8 KB
    __shared__ float psum[4][32][4];      // kh=1 partials, 2 KB
    int tid = threadIdx.x;
    int jl = tid & 31;
    int bb = (tid >> 5) & 3;
    int kh = tid >> 7;                    // 0 or 1
    int j  = blockIdx.x * 32 + jl;
    int b  = blockIdx.y * 4 + bb;

    if (t > 0) {
        for (int r = 0; r < 2; r++) {
            int i4 = tid + r * 256;
            int sb = i4 >> 7, k4 = (i4 & 127) << 2;
            *(float4*)(&hsh[sb][k4]) =
                *(const float4*)(hs + ((size_t)(blockIdx.y * 4 + sb) * SEQ + (t - 1)) * HIDDEN + k4);
        }
        __syncthreads();
    }

    float ai = 0.f, af = 0.f, ag = 0.f, ao = 0.f;

    if (t > 0) {
        const float* hp = hsh[bb];
        if (bf) {
            const ushort_t* wt = (const ushort_t*)WT;
            const ushort_t* p0 = wt + (size_t)j * 8;
            const ushort_t* p1 = wt + (size_t)(HIDDEN + j) * 8;
            const ushort_t* p2 = wt + (size_t)(2 * HIDDEN + j) * 8;
            const ushort_t* p3 = wt + (size_t)(3 * HIDDEN + j) * 8;
#pragma unroll 2
            for (int k8 = kh * 32; k8 < kh * 32 + 32; ++k8) {
                size_t pb = (size_t)k8 * 16384;
                uint4 u0 = *(const uint4*)(p0 + pb);
                uint4 u1 = *(const uint4*)(p1 + pb);
                uint4 u2 = *(const uint4*)(p2 + pb);
                uint4 u3 = *(const uint4*)(p3 + pb);
                float4 h0 = *(const float4*)(hp + k8 * 8);
                float4 h1 = *(const float4*)(hp + k8 * 8 + 4);
                float w[8];
                bfpair(u0.x, w[0], w[1]); bfpair(u0.y, w[2], w[3]);
                bfpair(u0.z, w[4], w[5]); bfpair(u0.w, w[6], w[7]);
                ai += w[0]*h0.x + w[1]*h0.y + w[2]*h0.z + w[3]*h0.w
                    + w[4]*h1.x + w[5]*h1.y + w[6]*h1.z + w[7]*h1.w;
                bfpair(u1.x, w[0], w[1]); bfpair(u1.y, w[2], w[3]);
                bfpair(u1.z, w[4], w[5]); bfpair(u1.w, w[6], w[7]);
                af += w[0]*h0.x + w[1]*h0.y + w[2]*h0.z + w[3]*h0.w
                    + w[4]*h1.x + w[5]*h1.y + w[6]*h1.z + w[7]*h1.w;
                bfpair(u2.x, w[0], w[1]); bfpair(u2.y, w[2], w[3]);
                bfpair(u2.z, w[4], w[5]); bfpair(u2.w, w[6], w[7]);
                ag += w[0]*h0.x + w[1]*h0.y + w[2]*h0.z + w[3]*h0.w
                    + w[4]*h1.x + w[5]*h1.y + w[6]*h1.z + w[7]*h1.w;
                bfpair(u3.x, w[0], w[1]); bfpair(u3.y, w[2], w[3]);
                bfpair(u3.z, w[4], w[5]); bfpair(u3.w, w[6], w[7]);
                ao += w[0]*h0.x + w[1]*h0.y + w[2]*h0.z + w[3]*h0.w
                    + w[4]*h1.x + w[5]*h1.y + w[6]*h1.z + w[7]*h1.w;
            }
        } else {
            const float* wt = (const float*)WT;
            const float* p0 = wt + (size_t)j * 4;
            const float* p1 = wt + (size_t)(HIDDEN + j) * 4;
            const float* p2 = wt + (size_t)(2 * HIDDEN + j) * 4;
            const float* p3 = wt + (size_t)(3 * HIDDEN + j) * 4;
#pragma unroll 4
            for (int k4 = kh * 64; k4 < kh * 64 + 64; ++k4) {
                size_t pb = (size_t)k4 * 8192;
                float4 wi = *(const float4*)(p0 + pb);
                float4 wf = *(const float4*)(p1 + pb);
                float4 wg = *(const float4*)(p2 + pb);
                float4 wo = *(const float4*)(p3 + pb);
                float4 hv = *(const float4*)(hp + k4 * 4);
                ai += wi.x*hv.x + wi.y*hv.y + wi.z*hv.z + wi.w*hv.w;
                af += wf.x*hv.x + wf.y*hv.y + wf.z*hv.z + wf.w*hv.w;
                ag += wg.x*hv.x + wg.y*hv.y + wg.z*hv.z + wg.w*hv.w;
                ao += wo.x*hv.x + wo.y*hv.y + wo.z*hv.z + wo.w*hv.w;
            }
        }
        // combine split-K partials (barrier is uniform: t is a kernel arg)
        if (kh == 1) {
            psum[bb][jl][0] = ai; psum[bb][jl][1] = af;
            psum[bb][jl][2] = ag; psum[bb][jl][3] = ao;
        }
        __syncthreads();
        if (kh == 0) {
            ai += psum[bb][jl][0]; af += psum[bb][jl][1];
            ag += psum[bb][jl][2]; ao += psum[bb][jl][3];
        }
    }

    if (kh == 1) return;                  // no barriers beyond this point

    size_t xbase = ((size_t)b * SEQ + t) * G4;
    ai += xp[xbase + j];
    af += xp[xbase + HIDDEN + j];
    ag += xp[xbase + 2 * HIDDEN + j];
    ao += xp[xbase + 3 * HIDDEN + j];

    float c_prev = (t > 0) ? c_buf[b * HIDDEN + j] : 0.0f;
    float c = sigm(af) * c_prev + sigm(ai) * tanhf(ag);
    float h = sigm(ao) * tanhf(c);
    c_buf[b * HIDDEN + j] = c;
    hs[((size_t)b * SEQ + t) * HIDDEN + j] = h;
}

// ---------------------------------------------------------------------------
// K2 fallback (old, W_hh direct) — only if workspace too small for WT.
// ---------------------------------------------------------------------------
template<bool BF>
__global__ void k_step(const int* __restrict__ mode,
                       const float* __restrict__ xp,
                       const void* __restrict__ W_hh,
                       float* __restrict__ c_buf,
                       float* __restrict__ hs,
                       int t) {
    if (*mode != (int)BF) return;
    __shared__ float hsh[4][HIDDEN];
    int tid = threadIdx.x;
    int jl  = tid & 63, bb = tid >> 6;
    int j   = blockIdx.x * 64 + jl;
    int b   = blockIdx.y * 4 + bb;

    if (t > 0) {
        for (int r = 0; r < 2; r++) {
            int i4 = tid + r * 256;
            int sb = i4 >> 7, k4 = (i4 & 127) << 2;
            *(float4*)(&hsh[sb][k4]) =
                *(const float4*)(hs + ((size_t)(blockIdx.y * 4 + sb) * SEQ + (t - 1)) * HIDDEN + k4);
        }
        __syncthreads();
    }

    size_t xbase = ((size_t)b * SEQ + t) * G4;
    float ai = xp[xbase + j];
    float af = xp[xbase + HIDDEN + j];
    float ag = xp[xbase + 2 * HIDDEN + j];
    float ao = xp[xbase + 3 * HIDDEN + j];

    if (t > 0) {
        const float* hp = hsh[bb];
        size_t r0 = (size_t)j * HIDDEN;
        size_t r1 = (size_t)(HIDDEN + j) * HIDDEN;
        size_t r2 = (size_t)(2 * HIDDEN + j) * HIDDEN;
        size_t r3 = (size_t)(3 * HIDDEN + j) * HIDDEN;
        for (int k = 0; k < HIDDEN; k += 8) {
            float w[8];
            ldw8<BF>(W_hh, r0 + k, w); ai += dot8f(w, hp + k);
            ldw8<BF>(W_hh, r1 + k, w); af += dot8f(w, hp + k);
            ldw8<BF>(W_hh, r2 + k, w); ag += dot8f(w, hp + k);
            ldw8<BF>(W_hh, r3 + k, w); ao += dot8f(w, hp + k);
        }
    }

    float c_prev = (t > 0) ? c_buf[b * HIDDEN + j] : 0.0f;
    float c = sigm(af) * c_prev + sigm(ai) * tanhf(ag);
    float h = sigm(ao) * tanhf(c);
    c_buf[b * HIDDEN + j] = c;
    hs[((size_t)b * SEQ + t) * HIDDEN + j] = h;
}

// ---------------------------------------------------------------------------
// K3 v4: logits = hs @ W_out^T + b_out.  M=2112, N=32000, K=512.
// R1's vector-load staging (proven FETCH ~312MB) + XOR-swizzled LDS layout:
// element (m,k) lives at As[k][swz(m) ^ ((k>>2)<<2)].
//   write inst (fixed d): banks = (m&3) | kq<<2 -> 32 distinct / 64 lanes = free
//   read: col = (tm*4+i)^kx -> m = 8tm+i (same fragment map as R1; epilogue
//   unchanged). a-reads broadcast, b-reads 2-way -> free (m136).
// ---------------------------------------------------------------------------
#define BM 128
#define BN 128
#define KC 32
#define NBN 250              // 32000 / 128
#define NBM 17               // ceil(2112 / 128)
#define LOGITS_GRID (8 * 32 * NBM)   // 4352

__device__ __forceinline__ int swz(int r) {   // bijective on 0..127
    return ((r >> 2) & 1) * 64 + (r >> 3) * 4 + (r & 3);
}

template<bool BF>
__global__ __launch_bounds__(256, 4)
void k_logits(const int* __restrict__ mode,
              const float* __restrict__ hs,
              const void* __restrict__ W_out,
              const void* __restrict__ b_out,
              void* __restrict__ out) {
    if (*mode != (int)BF) return;

    int bid = blockIdx.x;
    int xcd = bid & 7;
    int j8  = bid >> 3;
    int mb  = j8 % NBM;
    int nb  = xcd + 8 * (j8 / NBM);
    if (nb >= NBN) return;

    __shared__ float As[KC][BM];
    __shared__ float Bs[KC][BN];

    int t  = threadIdx.x;
    int tm = t >> 4;               // 0..15
    int tn = t & 15;               // 0..15
    int m_base = mb * BM;
    int n_base = nb * BN;

    float acc[8][8];
#pragma unroll
    for (int i = 0; i < 8; ++i)
#pragma unroll
        for (int q = 0; q < 8; ++q) acc[i][q] = 0.0f;

    for (int kt = 0; kt < HIDDEN / KC; ++kt) {
        __syncthreads();           // previous-iter readers done before overwrite

        // ---- stage A (hs): 128x32 f32, coalesced float4 row-chunk loads ----
#pragma unroll
        for (int i = 0; i < 4; ++i) {
            int flat = t + i * 256;        // float4 id 0..1023
            int m  = flat >> 3;            // 0..127
            int kq = flat & 7;             // 0..7
            int gm = m_base + m;
            float4 v = make_float4(0.f, 0.f, 0.f, 0.f);
            if (gm < MROWS)
                v = *(const float4*)(hs + (size_t)gm * HIDDEN + kt * KC + kq * 4);
            int col = swz(m) ^ (kq << 2);
            As[kq*4+0][col] = v.x; As[kq*4+1][col] = v.y;
            As[kq*4+2][col] = v.z; As[kq*4+3][col] = v.w;
        }

        // ---- stage B (W_out): 128x32, dtype-dependent vector loads ----
        if constexpr (BF) {
#pragma unroll
            for (int i = 0; i < 2; ++i) {
                int flat = t + i * 256;    // uint4 id 0..511 (8 bf16 each)
                int n  = flat >> 2;        // 0..127
                int ko = (flat & 3) * 8;   // 0,8,16,24
                const ushort_t* src = (const ushort_t*)W_out
                    + (size_t)(n_base + n) * HIDDEN + kt * KC + ko;
                uint4 u = *(const uint4*)src;
                float w[8];
                bfpair(u.x, w[0], w[1]); bfpair(u.y, w[2], w[3]);
                bfpair(u.z, w[4], w[5]); bfpair(u.w, w[6], w[7]);
                int sb = swz(n);
#pragma unroll
                for (int d = 0; d < 8; ++d) {
                    int kq = (ko + d) >> 2;
                    Bs[ko + d][sb ^ (kq << 2)] = w[d];
                }
            }
        } else {
#pragma unroll
            for (int i = 0; i < 4; ++i) {
                int flat = t + i * 256;
                int n  = flat >> 3;
                int kq = flat & 7;
                const float* src = (const float*)W_out
                    + (size_t)(n_base + n) * HIDDEN + kt * KC + kq * 4;
                float4 v = *(const float4*)src;
                int col = swz(n) ^ (kq << 2);
                Bs[kq*4+0][col] = v.x; Bs[kq*4+1][col] = v.y;
                Bs[kq*4+2][col] = v.z; Bs[kq*4+3][col] = v.w;
            }
        }
        __syncthreads();

        // ---- inner: 32 k-steps, 64 FMA per 4 ds_read_b128 (conflict-free) --
#pragma unroll 8
        for (int k = 0; k < KC; ++k) {
            int kx = k & 28;               // (k>>2)<<2
            float4 a0 = *(const float4*)&As[k][(tm * 4) ^ kx];
            float4 a1 = *(const float4*)&As[k][64 + ((tm * 4) ^ kx)];
            float4 b0 = *(const float4*)&Bs[k][(tn * 4) ^ kx];
            float4 b1 = *(const float4*)&Bs[k][64 + ((tn * 4) ^ kx)];
            float a[8] = {a0.x, a0.y, a0.z, a0.w, a1.x, a1.y, a1.z, a1.w};
            float b[8] = {b0.x, b0.y, b0.z, b0.w, b1.x, b1.y, b1.z, b1.w};
#pragma unroll
            for (int i = 0; i < 8; ++i)
#pragma unroll
                for (int q = 0; q < 8; ++q)
                    acc[i][q] = fmaf(a[i], b[q], acc[i][q]);
        }
    }

    // ---- epilogue (R1-identical): thread owns m=8tm+i, n=8tn+q ----
    float bias[8];
#pragma unroll
    for (int q = 0; q < 8; ++q) bias[q] = ldw1<BF>(b_out, n_base + tn * 8 + q);

#pragma unroll
    for (int i = 0; i < 8; ++i) {
        int gm = m_base + tm * 8 + i;
        if (gm >= MROWS) continue;
        size_t o = (size_t)gm * VOCAB + n_base + tn * 8;
        if constexpr (BF) {
            unsigned int p[4];
#pragma unroll
            for (int q = 0; q < 4; ++q) {
                __hip_bfloat16 lo = __float2bfloat16(acc[i][2*q]   + bias[2*q]);
                __hip_bfloat16 hi = __float2bfloat16(acc[i][2*q+1] + bias[2*q+1]);
                unsigned short ul = *(unsigned short*)&lo;
                unsigned short uh = *(unsigned short*)&hi;
                p[q] = (unsigned int)ul | ((unsigned int)uh << 16);
            }
            *(uint4*)((__hip_bfloat16*)out + o) = make_uint4(p[0], p[1], p[2], p[3]);
        } else {
            float* op = (float*)out + o;
            *(float4*)(op + 0) = make_float4(acc[i][0]+bias[0], acc[i][1]+bias[1],
                                             acc[i][2]+bias[2], acc[i][3]+bias[3]);
            *(float4*)(op + 4) = make_float4(acc[i][4]+bias[4], acc[i][5]+bias[5],
                                             acc[i][6]+bias[6], acc[i][7]+bias[7]);
        }
    }
}

// ---------------------------------------------------------------------------
extern "C" void kernel_launch(void* const* d_in, const int* in_sizes, int n_in,
                              void* d_out, int out_size, void* d_ws, size_t ws_size,
                              hipStream_t stream) {
    const void* features  = d_in[0];
    const int*  captions  = (const int*)d_in[1];
    const void* embedding = d_in[3];
    const void* W_ih      = d_in[4];
    const void* W_hh      = d_in[5];
    const void* b_ih      = d_in[6];
    const void* b_hh      = d_in[7];
    const void* W_out     = d_in[8];
    const void* b_out     = d_in[9];

    // ws layout: xp[2112][2048] f32 | hs[2112][512] f32 | c_buf[64][512] f32 |
    //            mode (int) | pad | WT (4MB repacked W_hh)
    char* ws = (char*)d_ws;
    const size_t XP_OFF = 0;
    const size_t HS_OFF = (size_t)2112 * G4 * 4;
    const size_t CB_OFF = HS_OFF + (size_t)2112 * HIDDEN * 4;
    const size_t MODE_OFF = CB_OFF + (size_t)BATCH * HIDDEN * 4;
    const size_t WT_OFF = MODE_OFF + 16;
    const size_t NEED = WT_OFF + (size_t)4 * 1024 * 1024;

    float* xp    = (float*)(ws + XP_OFF);
    float* hs    = (float*)(ws + HS_OFF);
    float* c_buf = (float*)(ws + CB_OFF);
    int*   mode  = (int*)(ws + MODE_OFF);
    void*  WT    = (void*)(ws + WT_OFF);

    const bool fast = (ws_size >= NEED);

    k_detect<<<1, 256, 0, stream>>>((const unsigned int*)features, mode);

    if (fast)
        k_wtr<<<1024, 256, 0, stream>>>(mode, W_hh, WT);

    k_xproj<false><<<dim3(8, BATCH * SEQ), 256, 0, stream>>>(
        mode, features, captions, embedding, W_ih, b_ih, b_hh, xp);
    k_xproj<true><<<dim3(8, BATCH * SEQ), 256, 0, stream>>>(
        mode, features, captions, embedding, W_ih, b_ih, b_hh, xp);

    for (int t = 0; t < SEQ; t++) {
        if (fast) {
            k_step3<<<dim3(16, BATCH / 4), 256, 0, stream>>>(mode, xp, WT, c_buf, hs, t);
        } else {
            k_step<false><<<dim3(8, BATCH / 4), 256, 0, stream>>>(mode, xp, W_hh, c_buf, hs, t);
            k_step<true><<<dim3(8, BATCH / 4), 256, 0, stream>>>(mode, xp, W_hh, c_buf, hs, t);
        }
    }

    k_logits<false><<<dim3(LOGITS_GRID), 256, 0, stream>>>(mode, hs, W_out, b_out, d_out);
    k_logits<true><<<dim3(LOGITS_GRID), 256, 0, stream>>>(mode, hs, W_out, b_out, d_out);
}